// Round 1
// baseline (518.743 us; speedup 1.0000x reference)
//
#include <hip/hip_runtime.h>

// B=8, C=128, H=96, W=96, D=4
// Single activation buffer "act": [b][d][h][w][kappa] bf16, channel axis stored
// in permuted kappa-order. sigma(kappa) = true channel. Scans run IN PLACE:
//   transpose: x -> act (x in kappa-order)
//   row_kernel: act rows 1..95 <- row-scan outputs (reads rows h+1.. which
//               still hold x), row 0 untouched (= x row 0 = hs row 0)
//   col_kernel: act cols 0..95 <- col-scan outputs (reads cols w+1.. which
//               still hold hs)
//   out_kernel: out = x + unpermute(act)

typedef short bf16x8 __attribute__((ext_vector_type(8)));
typedef float f32x4 __attribute__((ext_vector_type(4)));
typedef unsigned int uint4v __attribute__((ext_vector_type(4)));

__device__ __forceinline__ unsigned short f2bf(float f) {
  unsigned int u = __builtin_bit_cast(unsigned int, f);
  u = (u + 0x7FFFu + ((u >> 16) & 1u)) >> 16;
  return (unsigned short)u;
}
__device__ __forceinline__ float bf2f(unsigned short h) {
  unsigned int u = ((unsigned int)h) << 16;
  return __builtin_bit_cast(float, u);
}

// kappa = kt*32 + q*8 + j  ->  true channel c = kt*32 + (j>>2)*16 + q*4 + (j&3)
// Closure: lane(q)'s D-output acc[mi][r] (channel mi*16+q*4+r) is exactly the
// element it needs at B-slot (kt=mi>>1, j=(mi&1)*4+r) next step.
__device__ __forceinline__ int sigma_k(int kap) {
  int kt = kap >> 5, q = (kap >> 3) & 3, j = kap & 7;
  return kt * 32 + ((j >> 2) << 4) + q * 4 + (j & 3);
}

// ---------------- prep: cast weights to bf16 (columns kappa-permuted), sum biases
__global__ __launch_bounds__(256) void prep_kernel(
    const float* __restrict__ W1, const float* __restrict__ b1,
    const float* __restrict__ W2, const float* __restrict__ b2,
    const float* __restrict__ W4, const float* __restrict__ b4,
    const float* __restrict__ W5, const float* __restrict__ b5,
    unsigned short* __restrict__ Wb, float* __restrict__ bs12,
    float* __restrict__ bs45) {
  int gid = blockIdx.x * 256 + threadIdx.x;
  if (gid < 4 * 65536) {
    int m = gid >> 16;
    int r = gid & 65535;          // d*16384 + rho*128 + kappa
    int kap = r & 127;
    int c = sigma_k(kap);
    const float* src = (m == 0) ? W1 : (m == 1) ? W2 : (m == 2) ? W4 : W5;
    Wb[m * 65536 + r] = f2bf(src[(r >> 7) * 128 + c]);
  } else if (gid < 4 * 65536 + 512) {
    int r = gid - 4 * 65536;
    bs12[r] = b1[r] + b2[r];
  } else if (gid < 4 * 65536 + 1024) {
    int r = gid - 4 * 65536 - 512;
    bs45[r] = b4[r] + b5[r];
  }
}

// ---------------- transpose x -> act bf16 [b][d][h][w][kappa] ----------------
__global__ __launch_bounds__(256) void transpose_kernel(
    const float* __restrict__ x, unsigned short* __restrict__ act) {
  __shared__ unsigned short tile[128 * 208];
  int bid = blockIdx.x;
  int half = bid & 1;
  int rest = bid >> 1;
  int h = rest % 96;
  int b = rest / 96;
  int wd0 = half * 192;
  int tid = threadIdx.x;
  // gather: x rows, 768-B contiguous runs, write b128 swizzled rows (true c)
#pragma unroll
  for (int it = 0; it < 12; ++it) {
    int cid = it * 256 + tid;
    int c = cid / 24;
    int k = cid % 24;
    const float* xp = x + ((size_t)(b * 128 + c) * 96 + h) * 384 + wd0 + k * 8;
    float4 v0 = *(const float4*)xp;
    float4 v1 = *(const float4*)(xp + 4);
    bf16x8 pk;
    pk[0] = (short)f2bf(v0.x); pk[1] = (short)f2bf(v0.y);
    pk[2] = (short)f2bf(v0.z); pk[3] = (short)f2bf(v0.w);
    pk[4] = (short)f2bf(v1.x); pk[5] = (short)f2bf(v1.y);
    pk[6] = (short)f2bf(v1.z); pk[7] = (short)f2bf(v1.w);
    int ks = k ^ ((c >> 3) & 7);
    *(bf16x8*)&tile[c * 208 + ks * 8] = pk;
  }
  __syncthreads();
  // scatter: gather sigma-permuted channels per kappa-run, 16B act writes
#pragma unroll
  for (int it = 0; it < 12; ++it) {
    int sid = it * 256 + tid;
    int wdl = sid >> 4;
    int cc = sid & 15;              // kappa0 = cc*8
    int k = wdl >> 3, off = wdl & 7;
    int ktq = cc >> 2, qq = cc & 3;
    bf16x8 pk;
#pragma unroll
    for (int j = 0; j < 8; ++j) {
      int c = ktq * 32 + ((j >> 2) << 4) + qq * 4 + (j & 3);
      int ks = k ^ ((c >> 3) & 7);
      pk[j] = (short)tile[c * 208 + ks * 8 + off];
    }
    int wdg = wd0 + wdl;
    int d = wdg & 3, w = wdg >> 2;
    *(bf16x8*)(act + ((((size_t)(b * 4 + d) * 96 + h) * 96 + w) * 128 + cc * 8)) = pk;
  }
}

// One scan step: CUR (= bias + Wff@input_h) += Wrec@Bp; relu+pack -> Bp; store;
// NXT = bias + Wff@BN; refill BN from PF. Uses locals A1, A2, bias, Bp, outrow,
// OUT_STRIDE defined in the enclosing kernel.
#define SCAN_STEP(CUR, NXT, BN, PF)                                            \
  do {                                                                         \
    _Pragma("unroll") for (int kt = 0; kt < 4; ++kt)                           \
      _Pragma("unroll") for (int mi = 0; mi < 8; ++mi)                         \
        CUR[mi] = __builtin_amdgcn_mfma_f32_16x16x32_bf16(A2[mi][kt], Bp[kt],  \
                                                          CUR[mi], 0, 0, 0);   \
    _Pragma("unroll") for (int kt = 0; kt < 4; ++kt) {                         \
      unsigned int u0, u1, u2, u3;                                             \
      float a0 = fmaxf(CUR[2 * kt][0], 0.f);                                   \
      float a1 = fmaxf(CUR[2 * kt][1], 0.f);                                   \
      float a2 = fmaxf(CUR[2 * kt][2], 0.f);                                   \
      float a3 = fmaxf(CUR[2 * kt][3], 0.f);                                   \
      float c0 = fmaxf(CUR[2 * kt + 1][0], 0.f);                               \
      float c1 = fmaxf(CUR[2 * kt + 1][1], 0.f);                               \
      float c2 = fmaxf(CUR[2 * kt + 1][2], 0.f);                               \
      float c3 = fmaxf(CUR[2 * kt + 1][3], 0.f);                               \
      asm("v_cvt_pk_bf16_f32 %0, %1, %2" : "=v"(u0) : "v"(a0), "v"(a1));       \
      asm("v_cvt_pk_bf16_f32 %0, %1, %2" : "=v"(u1) : "v"(a2), "v"(a3));       \
      asm("v_cvt_pk_bf16_f32 %0, %1, %2" : "=v"(u2) : "v"(c0), "v"(c1));       \
      asm("v_cvt_pk_bf16_f32 %0, %1, %2" : "=v"(u3) : "v"(c2), "v"(c3));       \
      uint4v uu;                                                               \
      uu[0] = u0; uu[1] = u1; uu[2] = u2; uu[3] = u3;                          \
      Bp[kt] = __builtin_bit_cast(bf16x8, uu);                                 \
      *(bf16x8*)(outrow + kt * 32) = Bp[kt];                                   \
    }                                                                          \
    _Pragma("unroll") for (int mi = 0; mi < 8; ++mi)                           \
      NXT[mi] = __builtin_amdgcn_mfma_f32_16x16x32_bf16(A1[mi][0], BN[0],      \
                                                        bias[mi], 0, 0, 0);    \
    _Pragma("unroll") for (int kt = 1; kt < 4; ++kt)                           \
      _Pragma("unroll") for (int mi = 0; mi < 8; ++mi)                         \
        NXT[mi] = __builtin_amdgcn_mfma_f32_16x16x32_bf16(A1[mi][kt], BN[kt],  \
                                                          NXT[mi], 0, 0, 0);   \
    _Pragma("unroll") for (int kt = 0; kt < 4; ++kt)                           \
      BN[kt] = *(const bf16x8*)(PF + kt * 32);                                 \
    outrow += OUT_STRIDE;                                                      \
  } while (0)

// ---------------- row scan: one wave per (b,d,w-tile), M=128 in-wave ---------
__global__ __launch_bounds__(64, 1) void row_kernel(
    unsigned short* act, const unsigned short* __restrict__ Wb,
    const float* __restrict__ bs12) {
  int bid = blockIdx.x;
  int wt = bid % 6;
  int bd = bid / 6;  // b*4+d
  int d = bd & 3;
  int w0 = wt * 16;
  int lane = threadIdx.x & 63;
  int q = lane >> 4;
  int n = lane & 15;

  const unsigned short* w1p = Wb + d * 16384;
  const unsigned short* w2p = Wb + 65536 + d * 16384;

  bf16x8 A1[8][4], A2[8][4];
#pragma unroll
  for (int mi = 0; mi < 8; ++mi) {
    int c = mi * 16 + n;
#pragma unroll
    for (int kt = 0; kt < 4; ++kt) {
      int k0 = kt * 32 + q * 8;
      A1[mi][kt] = *(const bf16x8*)(w1p + c * 128 + k0);
      A2[mi][kt] = *(const bf16x8*)(w2p + c * 128 + k0);
    }
  }
  f32x4 bias[8];
#pragma unroll
  for (int mi = 0; mi < 8; ++mi)
#pragma unroll
    for (int r = 0; r < 4; ++r)
      bias[mi][r] = bs12[d * 128 + mi * 16 + q * 4 + r];

  size_t base = ((size_t)bd * 9216 + (size_t)(w0 + n)) * 128 + q * 8;
  const unsigned short* xrow = act + base;   // row h at + h*12288
  unsigned short* outrow = act + base + 12288;  // write ptr, starts at row 1
  const int OUT_STRIDE = 12288;

  bf16x8 Bp[4], Bn_[4], Bf_[4];
  // seed: prev = x row0 (raw); act row0 already holds it (in place, no store)
#pragma unroll
  for (int kt = 0; kt < 4; ++kt)
    Bp[kt] = *(const bf16x8*)(xrow + kt * 32);

  // prologue: accA_ = bias + W1 @ x(row1)
  f32x4 accA_[8], accB_[8];
#pragma unroll
  for (int kt = 0; kt < 4; ++kt)
    Bn_[kt] = *(const bf16x8*)(xrow + 12288 + kt * 32);
#pragma unroll
  for (int mi = 0; mi < 8; ++mi)
    accA_[mi] = __builtin_amdgcn_mfma_f32_16x16x32_bf16(A1[mi][0], Bn_[0],
                                                        bias[mi], 0, 0, 0);
#pragma unroll
  for (int kt = 1; kt < 4; ++kt)
#pragma unroll
    for (int mi = 0; mi < 8; ++mi)
      accA_[mi] = __builtin_amdgcn_mfma_f32_16x16x32_bf16(A1[mi][kt], Bn_[kt],
                                                          accA_[mi], 0, 0, 0);
  // prefetch x rows 2,3
#pragma unroll
  for (int kt = 0; kt < 4; ++kt) {
    Bn_[kt] = *(const bf16x8*)(xrow + 2 * 12288 + kt * 32);
    Bf_[kt] = *(const bf16x8*)(xrow + 3 * 12288 + kt * 32);
  }

#pragma unroll 1
  for (int h = 1; h <= 93; h += 2) {
    const unsigned short* pf1 =
        xrow + (size_t)(h + 3 <= 95 ? h + 3 : 95) * 12288;
    SCAN_STEP(accA_, accB_, Bn_, pf1);
    const unsigned short* pf2 =
        xrow + (size_t)(h + 4 <= 95 ? h + 4 : 95) * 12288;
    SCAN_STEP(accB_, accA_, Bf_, pf2);
  }
  {
    const unsigned short* pf3 = xrow + (size_t)95 * 12288;
    SCAN_STEP(accA_, accB_, Bn_, pf3);
  }
}

// ---------------- col scan: one wave per (b,d,h-tile), in place --------------
__global__ __launch_bounds__(64, 1) void col_kernel(
    unsigned short* act, const unsigned short* __restrict__ Wb,
    const float* __restrict__ bs45) {
  int bid = blockIdx.x;
  int ht = bid % 6;
  int bd = bid / 6;
  int d = bd & 3;
  int h0 = ht * 16;
  int lane = threadIdx.x & 63;
  int q = lane >> 4;
  int n = lane & 15;

  const unsigned short* w4p = Wb + 2 * 65536 + d * 16384;
  const unsigned short* w5p = Wb + 3 * 65536 + d * 16384;

  bf16x8 A1[8][4], A2[8][4];  // A1 = W4 (feed-forward), A2 = W5 (recurrent)
#pragma unroll
  for (int mi = 0; mi < 8; ++mi) {
    int c = mi * 16 + n;
#pragma unroll
    for (int kt = 0; kt < 4; ++kt) {
      int k0 = kt * 32 + q * 8;
      A1[mi][kt] = *(const bf16x8*)(w4p + c * 128 + k0);
      A2[mi][kt] = *(const bf16x8*)(w5p + c * 128 + k0);
    }
  }
  f32x4 bias[8];
#pragma unroll
  for (int mi = 0; mi < 8; ++mi)
#pragma unroll
    for (int r = 0; r < 4; ++r)
      bias[mi][r] = bs45[d * 128 + mi * 16 + q * 4 + r];

  size_t base = ((size_t)bd * 9216 + (size_t)(h0 + n) * 96) * 128 + q * 8;
  const unsigned short* ccol = act + base;  // col w at + w*128
  unsigned short* outrow = act + base;      // write ptr, starts at col 0
  const int OUT_STRIDE = 128;

  bf16x8 Bp[4], Bn_[4], Bf_[4];
  // seed: prev = relu(hs col0), written in place as hid col0
#pragma unroll
  for (int kt = 0; kt < 4; ++kt) {
    bf16x8 v = *(const bf16x8*)(ccol + kt * 32);
#pragma unroll
    for (int j = 0; j < 8; ++j) {
      unsigned short uv = (unsigned short)v[j];
      if (uv & 0x8000u) v[j] = 0;  // bf16 relu
    }
    Bp[kt] = v;
    *(bf16x8*)(outrow + kt * 32) = v;
  }
  outrow += 128;

  // prologue: accA_ = bias + W4 @ hs(col1) (raw)
  f32x4 accA_[8], accB_[8];
#pragma unroll
  for (int kt = 0; kt < 4; ++kt)
    Bn_[kt] = *(const bf16x8*)(ccol + 128 + kt * 32);
#pragma unroll
  for (int mi = 0; mi < 8; ++mi)
    accA_[mi] = __builtin_amdgcn_mfma_f32_16x16x32_bf16(A1[mi][0], Bn_[0],
                                                        bias[mi], 0, 0, 0);
#pragma unroll
  for (int kt = 1; kt < 4; ++kt)
#pragma unroll
    for (int mi = 0; mi < 8; ++mi)
      accA_[mi] = __builtin_amdgcn_mfma_f32_16x16x32_bf16(A1[mi][kt], Bn_[kt],
                                                          accA_[mi], 0, 0, 0);
  // prefetch cols 2,3
#pragma unroll
  for (int kt = 0; kt < 4; ++kt) {
    Bn_[kt] = *(const bf16x8*)(ccol + 2 * 128 + kt * 32);
    Bf_[kt] = *(const bf16x8*)(ccol + 3 * 128 + kt * 32);
  }

#pragma unroll 1
  for (int w = 1; w <= 93; w += 2) {
    const unsigned short* pf1 = ccol + (size_t)(w + 3 <= 95 ? w + 3 : 95) * 128;
    SCAN_STEP(accA_, accB_, Bn_, pf1);
    const unsigned short* pf2 = ccol + (size_t)(w + 4 <= 95 ? w + 4 : 95) * 128;
    SCAN_STEP(accB_, accA_, Bf_, pf2);
  }
  {
    const unsigned short* pf3 = ccol + (size_t)95 * 128;
    SCAN_STEP(accA_, accB_, Bn_, pf3);
  }
}

// ---------------- out = x + unpermute(act) ----------------
__global__ __launch_bounds__(256) void out_kernel(
    const float* __restrict__ x, const unsigned short* __restrict__ act,
    float* __restrict__ out) {
  __shared__ unsigned short tile[128 * 208];
  int bid = blockIdx.x;
  int half = bid & 1;
  int rest = bid >> 1;
  int h = rest % 96;
  int b = rest / 96;
  int wd0 = half * 192;
  int tid = threadIdx.x;
  // gather hid (kappa-order): 16B reads, scatter sigma-permuted into tile
#pragma unroll
  for (int it = 0; it < 12; ++it) {
    int gid = it * 256 + tid;
    int wdl = gid >> 4;
    int cc = gid & 15;              // kappa0 = cc*8
    int wdg = wd0 + wdl;
    int d = wdg & 3, w = wdg >> 2;
    bf16x8 v = *(const bf16x8*)(
        act + ((((size_t)(b * 4 + d) * 96 + h) * 96 + w) * 128 + cc * 8));
    int k = wdl >> 3, off = wdl & 7;
    int ktq = cc >> 2, qq = cc & 3;
#pragma unroll
    for (int j = 0; j < 8; ++j) {
      int c = ktq * 32 + ((j >> 2) << 4) + qq * 4 + (j & 3);
      int ks = k ^ ((c >> 3) & 7);
      tile[c * 208 + ks * 8 + off] = (unsigned short)v[j];
    }
  }
  __syncthreads();
  // scatter: b128 row reads, float4 x/out with 768-B runs
#pragma unroll
  for (int it = 0; it < 12; ++it) {
    int sid = it * 256 + tid;
    int c = sid / 24;
    int k = sid % 24;
    int ks = k ^ ((c >> 3) & 7);
    bf16x8 pk = *(const bf16x8*)&tile[c * 208 + ks * 8];
    size_t o = ((size_t)(b * 128 + c) * 96 + h) * 384 + wd0 + k * 8;
    float4 a0 = *(const float4*)(x + o);
    float4 a1 = *(const float4*)(x + o + 4);
    float4 r0, r1;
    r0.x = a0.x + bf2f((unsigned short)pk[0]);
    r0.y = a0.y + bf2f((unsigned short)pk[1]);
    r0.z = a0.z + bf2f((unsigned short)pk[2]);
    r0.w = a0.w + bf2f((unsigned short)pk[3]);
    r1.x = a1.x + bf2f((unsigned short)pk[4]);
    r1.y = a1.y + bf2f((unsigned short)pk[5]);
    r1.z = a1.z + bf2f((unsigned short)pk[6]);
    r1.w = a1.w + bf2f((unsigned short)pk[7]);
    *(float4*)(out + o) = r0;
    *(float4*)(out + o + 4) = r1;
  }
}

extern "C" void kernel_launch(void* const* d_in, const int* in_sizes, int n_in,
                              void* d_out, int out_size, void* d_ws,
                              size_t ws_size, hipStream_t stream) {
  (void)in_sizes; (void)n_in; (void)out_size; (void)ws_size;
  const float* x  = (const float*)d_in[0];
  const float* W1 = (const float*)d_in[1];
  const float* b1 = (const float*)d_in[2];
  const float* W2 = (const float*)d_in[3];
  const float* b2 = (const float*)d_in[4];
  const float* W4 = (const float*)d_in[5];
  const float* b4 = (const float*)d_in[6];
  const float* W5 = (const float*)d_in[7];
  const float* b5 = (const float*)d_in[8];
  float* out = (float*)d_out;

  char* ws = (char*)d_ws;
  unsigned short* Wb  = (unsigned short*)(ws);            // 524288 B
  float* bs12         = (float*)(ws + 524288);            // 2048 B
  float* bs45         = (float*)(ws + 526336);            // 2048 B
  unsigned short* act = (unsigned short*)(ws + 528384);   // 75497472 B

  prep_kernel<<<(4 * 65536 + 1024 + 255) / 256, 256, 0, stream>>>(
      W1, b1, W2, b2, W4, b4, W5, b5, Wb, bs12, bs45);
  transpose_kernel<<<8 * 96 * 2, 256, 0, stream>>>(x, act);
  row_kernel<<<192, 64, 0, stream>>>(act, Wb, bs12);
  col_kernel<<<192, 64, 0, stream>>>(act, Wb, bs45);
  out_kernel<<<8 * 96 * 2, 256, 0, stream>>>(x, act, out);
}

// Round 3
// 474.826 us; speedup vs baseline: 1.0925x; 1.0925x over previous
//
#include <hip/hip_runtime.h>

// B=8, C=128, H=96, W=96, D=4
// Single activation buffer "act": [b][d][h][w][kappa] bf16, channel axis stored
// in permuted kappa-order. sigma(kappa) = true channel. Scans run IN PLACE.
// Scan kernels use producer/consumer wave specialization:
//   wave1 (producer): ff_h = bias + Wff @ input_h  -> f32 LDS ring (4 slots)
//   wave0 (consumer): out_h = relu(ff_h + Wrec @ prev) -> pack -> global+regs
// Lock-free LDS flag sync; the two waves sit on different SIMDs so their
// MFMA issue/latency overlaps (a solo wave only achieves ~40cy/MFMA).
// Producer register rotation is 2-deep (Bn, Bf) => prefetch distance is 2.

typedef short bf16x8 __attribute__((ext_vector_type(8)));
typedef float f32x4 __attribute__((ext_vector_type(4)));
typedef unsigned int uint4v __attribute__((ext_vector_type(4)));

__device__ __forceinline__ unsigned short f2bf(float f) {
  unsigned int u = __builtin_bit_cast(unsigned int, f);
  u = (u + 0x7FFFu + ((u >> 16) & 1u)) >> 16;
  return (unsigned short)u;
}
__device__ __forceinline__ float bf2f(unsigned short h) {
  unsigned int u = ((unsigned int)h) << 16;
  return __builtin_bit_cast(float, u);
}

// kappa = kt*32 + q*8 + j  ->  true channel c = kt*32 + (j>>2)*16 + q*4 + (j&3)
__device__ __forceinline__ int sigma_k(int kap) {
  int kt = kap >> 5, q = (kap >> 3) & 3, j = kap & 7;
  return kt * 32 + ((j >> 2) << 4) + q * 4 + (j & 3);
}

// ---------------- prep: cast weights to bf16 (columns kappa-permuted), sum biases
__global__ __launch_bounds__(256) void prep_kernel(
    const float* __restrict__ W1, const float* __restrict__ b1,
    const float* __restrict__ W2, const float* __restrict__ b2,
    const float* __restrict__ W4, const float* __restrict__ b4,
    const float* __restrict__ W5, const float* __restrict__ b5,
    unsigned short* __restrict__ Wb, float* __restrict__ bs12,
    float* __restrict__ bs45) {
  int gid = blockIdx.x * 256 + threadIdx.x;
  if (gid < 4 * 65536) {
    int m = gid >> 16;
    int r = gid & 65535;          // d*16384 + rho*128 + kappa
    int kap = r & 127;
    int c = sigma_k(kap);
    const float* src = (m == 0) ? W1 : (m == 1) ? W2 : (m == 2) ? W4 : W5;
    Wb[m * 65536 + r] = f2bf(src[(r >> 7) * 128 + c]);
  } else if (gid < 4 * 65536 + 512) {
    int r = gid - 4 * 65536;
    bs12[r] = b1[r] + b2[r];
  } else if (gid < 4 * 65536 + 1024) {
    int r = gid - 4 * 65536 - 512;
    bs45[r] = b4[r] + b5[r];
  }
}

// ---------------- transpose x -> act bf16 [b][d][h][w][kappa] ----------------
__global__ __launch_bounds__(256) void transpose_kernel(
    const float* __restrict__ x, unsigned short* __restrict__ act) {
  __shared__ unsigned short tile[128 * 208];
  int bid = blockIdx.x;
  int half = bid & 1;
  int rest = bid >> 1;
  int h = rest % 96;
  int b = rest / 96;
  int wd0 = half * 192;
  int tid = threadIdx.x;
#pragma unroll
  for (int it = 0; it < 12; ++it) {
    int cid = it * 256 + tid;
    int c = cid / 24;
    int k = cid % 24;
    const float* xp = x + ((size_t)(b * 128 + c) * 96 + h) * 384 + wd0 + k * 8;
    float4 v0 = *(const float4*)xp;
    float4 v1 = *(const float4*)(xp + 4);
    bf16x8 pk;
    pk[0] = (short)f2bf(v0.x); pk[1] = (short)f2bf(v0.y);
    pk[2] = (short)f2bf(v0.z); pk[3] = (short)f2bf(v0.w);
    pk[4] = (short)f2bf(v1.x); pk[5] = (short)f2bf(v1.y);
    pk[6] = (short)f2bf(v1.z); pk[7] = (short)f2bf(v1.w);
    int ks = k ^ ((c >> 3) & 7);
    *(bf16x8*)&tile[c * 208 + ks * 8] = pk;
  }
  __syncthreads();
#pragma unroll
  for (int it = 0; it < 12; ++it) {
    int sid = it * 256 + tid;
    int wdl = sid >> 4;
    int cc = sid & 15;              // kappa0 = cc*8
    int k = wdl >> 3, off = wdl & 7;
    int ktq = cc >> 2, qq = cc & 3;
    bf16x8 pk;
#pragma unroll
    for (int j = 0; j < 8; ++j) {
      int c = ktq * 32 + ((j >> 2) << 4) + qq * 4 + (j & 3);
      int ks = k ^ ((c >> 3) & 7);
      pk[j] = (short)tile[c * 208 + ks * 8 + off];
    }
    int wdg = wd0 + wdl;
    int d = wdg & 3, w = wdg >> 2;
    *(bf16x8*)(act + ((((size_t)(b * 4 + d) * 96 + h) * 96 + w) * 128 + cc * 8)) = pk;
  }
}

// ---------------- row scan: 2 waves/block, producer+consumer ----------------
__global__ __launch_bounds__(128) void row_kernel(
    unsigned short* act, const unsigned short* __restrict__ Wb,
    const float* __restrict__ bs12) {
  __shared__ float slots[4][8][64][4];  // [slot][mi][lane][4] = 32KB
  __shared__ int flags[64];             // [0]=prod, [32]=cons
  int bid = blockIdx.x;
  int wt = bid % 6;
  int bd = bid / 6;  // b*4+d
  int d = bd & 3;
  int w0 = wt * 16;
  int tid = threadIdx.x;
  int wave = tid >> 6;
  int lane = tid & 63;
  int q = lane >> 4;
  int n = lane & 15;
  volatile int* fprod = &flags[0];
  volatile int* fcons = &flags[32];
  if (tid < 2) flags[tid * 32] = 0;
  __syncthreads();

  size_t bd9216 = (size_t)bd * 9216;
  size_t base = (bd9216 + (size_t)(w0 + n)) * 128 + q * 8;

  if (wave == 1) {
    // ---- ff producer: slot[h&3] = bias + W1 @ x_h ----
    const unsigned short* w1p = Wb + d * 16384;
    bf16x8 A1[8][4];
#pragma unroll
    for (int mi = 0; mi < 8; ++mi) {
      int c = mi * 16 + n;
#pragma unroll
      for (int kt = 0; kt < 4; ++kt)
        A1[mi][kt] = *(const bf16x8*)(w1p + c * 128 + kt * 32 + q * 8);
    }
    f32x4 bias[8];
#pragma unroll
    for (int mi = 0; mi < 8; ++mi)
#pragma unroll
      for (int r = 0; r < 4; ++r)
        bias[mi][r] = bs12[d * 128 + mi * 16 + q * 4 + r];
    const unsigned short* xrow = act + base;
    bf16x8 Bn[4], Bf[4];
    // invariant at loop entry h: Bn = x row h, Bf = x row h+1
#pragma unroll
    for (int kt = 0; kt < 4; ++kt) {
      Bn[kt] = *(const bf16x8*)(xrow + (size_t)1 * 12288 + kt * 32);
      Bf[kt] = *(const bf16x8*)(xrow + (size_t)2 * 12288 + kt * 32);
    }
#pragma unroll 1
    for (int h = 1; h <= 95; ++h) {
      while (h - *fcons > 3) __builtin_amdgcn_s_sleep(1);
      asm volatile("" ::: "memory");
      f32x4 acc[8];
#pragma unroll
      for (int mi = 0; mi < 8; ++mi)
        acc[mi] = __builtin_amdgcn_mfma_f32_16x16x32_bf16(A1[mi][0], Bn[0],
                                                          bias[mi], 0, 0, 0);
#pragma unroll
      for (int kt = 1; kt < 4; ++kt)
#pragma unroll
        for (int mi = 0; mi < 8; ++mi)
          acc[mi] = __builtin_amdgcn_mfma_f32_16x16x32_bf16(A1[mi][kt], Bn[kt],
                                                            acc[mi], 0, 0, 0);
      int hp = (h + 2 <= 95) ? h + 2 : 95;  // 2-deep rotation => distance 2
      const unsigned short* pf = xrow + (size_t)hp * 12288;
#pragma unroll
      for (int kt = 0; kt < 4; ++kt) {
        Bn[kt] = Bf[kt];
        Bf[kt] = *(const bf16x8*)(pf + kt * 32);
      }
      float* sp = &slots[h & 3][0][lane][0];
#pragma unroll
      for (int mi = 0; mi < 8; ++mi)
        *(f32x4*)(sp + mi * 256) = acc[mi];
      asm volatile("s_waitcnt lgkmcnt(0)" ::: "memory");
      if (lane == 0) *fprod = h;
    }
  } else {
    // ---- rec consumer: act_h = relu(slot[h] + W2 @ prev) ----
    const unsigned short* w2p = Wb + 65536 + d * 16384;
    bf16x8 A2[8][4];
#pragma unroll
    for (int mi = 0; mi < 8; ++mi) {
      int c = mi * 16 + n;
#pragma unroll
      for (int kt = 0; kt < 4; ++kt)
        A2[mi][kt] = *(const bf16x8*)(w2p + c * 128 + kt * 32 + q * 8);
    }
    const unsigned short* xrow = act + base;
    unsigned short* outrow = act + base + 12288;
    bf16x8 Bp[4];
#pragma unroll
    for (int kt = 0; kt < 4; ++kt)
      Bp[kt] = *(const bf16x8*)(xrow + kt * 32);  // row0 seed (in place)
#pragma unroll 1
    for (int h = 1; h <= 95; ++h) {
      while (*fprod < h) __builtin_amdgcn_s_sleep(1);
      asm volatile("" ::: "memory");
      const float* sp = &slots[h & 3][0][lane][0];
      f32x4 acc[8];
#pragma unroll
      for (int mi = 0; mi < 8; ++mi)
        acc[mi] = *(const f32x4*)(sp + mi * 256);
#pragma unroll
      for (int kt = 0; kt < 4; ++kt)
#pragma unroll
        for (int mi = 0; mi < 8; ++mi)
          acc[mi] = __builtin_amdgcn_mfma_f32_16x16x32_bf16(A2[mi][kt], Bp[kt],
                                                            acc[mi], 0, 0, 0);
#pragma unroll
      for (int kt = 0; kt < 4; ++kt) {
        unsigned int u0, u1, u2, u3;
        float a0 = fmaxf(acc[2 * kt][0], 0.f);
        float a1 = fmaxf(acc[2 * kt][1], 0.f);
        float a2 = fmaxf(acc[2 * kt][2], 0.f);
        float a3 = fmaxf(acc[2 * kt][3], 0.f);
        float c0 = fmaxf(acc[2 * kt + 1][0], 0.f);
        float c1 = fmaxf(acc[2 * kt + 1][1], 0.f);
        float c2 = fmaxf(acc[2 * kt + 1][2], 0.f);
        float c3 = fmaxf(acc[2 * kt + 1][3], 0.f);
        asm("v_cvt_pk_bf16_f32 %0, %1, %2" : "=v"(u0) : "v"(a0), "v"(a1));
        asm("v_cvt_pk_bf16_f32 %0, %1, %2" : "=v"(u1) : "v"(a2), "v"(a3));
        asm("v_cvt_pk_bf16_f32 %0, %1, %2" : "=v"(u2) : "v"(c0), "v"(c1));
        asm("v_cvt_pk_bf16_f32 %0, %1, %2" : "=v"(u3) : "v"(c2), "v"(c3));
        uint4v uu;
        uu[0] = u0; uu[1] = u1; uu[2] = u2; uu[3] = u3;
        Bp[kt] = __builtin_bit_cast(bf16x8, uu);
        *(bf16x8*)(outrow + kt * 32) = Bp[kt];
      }
      outrow += 12288;
      asm volatile("" ::: "memory");
      if (lane == 0) *fcons = h;
    }
  }
}

// ---------------- col scan: 2 waves/block, producer+consumer, in place -------
__global__ __launch_bounds__(128) void col_kernel(
    unsigned short* act, const unsigned short* __restrict__ Wb,
    const float* __restrict__ bs45) {
  __shared__ float slots[4][8][64][4];
  __shared__ int flags[64];
  int bid = blockIdx.x;
  int ht = bid % 6;
  int bd = bid / 6;
  int d = bd & 3;
  int h0 = ht * 16;
  int tid = threadIdx.x;
  int wave = tid >> 6;
  int lane = tid & 63;
  int q = lane >> 4;
  int n = lane & 15;
  volatile int* fprod = &flags[0];
  volatile int* fcons = &flags[32];
  if (tid < 2) flags[tid * 32] = 0;
  __syncthreads();

  size_t bd9216 = (size_t)bd * 9216;
  size_t base = (bd9216 + (size_t)(h0 + n) * 96) * 128 + q * 8;

  if (wave == 1) {
    // ---- ff producer: slot[w&3] = bias + W4 @ hs_w ----
    const unsigned short* w4p = Wb + 2 * 65536 + d * 16384;
    bf16x8 A1[8][4];
#pragma unroll
    for (int mi = 0; mi < 8; ++mi) {
      int c = mi * 16 + n;
#pragma unroll
      for (int kt = 0; kt < 4; ++kt)
        A1[mi][kt] = *(const bf16x8*)(w4p + c * 128 + kt * 32 + q * 8);
    }
    f32x4 bias[8];
#pragma unroll
    for (int mi = 0; mi < 8; ++mi)
#pragma unroll
      for (int r = 0; r < 4; ++r)
        bias[mi][r] = bs45[d * 128 + mi * 16 + q * 4 + r];
    const unsigned short* ccol = act + base;
    bf16x8 Bn[4], Bf[4];
    // invariant at loop entry w: Bn = hs col w, Bf = hs col w+1
#pragma unroll
    for (int kt = 0; kt < 4; ++kt) {
      Bn[kt] = *(const bf16x8*)(ccol + (size_t)1 * 128 + kt * 32);
      Bf[kt] = *(const bf16x8*)(ccol + (size_t)2 * 128 + kt * 32);
    }
#pragma unroll 1
    for (int w = 1; w <= 95; ++w) {
      while (w - *fcons > 3) __builtin_amdgcn_s_sleep(1);
      asm volatile("" ::: "memory");
      f32x4 acc[8];
#pragma unroll
      for (int mi = 0; mi < 8; ++mi)
        acc[mi] = __builtin_amdgcn_mfma_f32_16x16x32_bf16(A1[mi][0], Bn[0],
                                                          bias[mi], 0, 0, 0);
#pragma unroll
      for (int kt = 1; kt < 4; ++kt)
#pragma unroll
        for (int mi = 0; mi < 8; ++mi)
          acc[mi] = __builtin_amdgcn_mfma_f32_16x16x32_bf16(A1[mi][kt], Bn[kt],
                                                            acc[mi], 0, 0, 0);
      int wp = (w + 2 <= 95) ? w + 2 : 95;  // 2-deep rotation => distance 2
      const unsigned short* pf = ccol + (size_t)wp * 128;
#pragma unroll
      for (int kt = 0; kt < 4; ++kt) {
        Bn[kt] = Bf[kt];
        Bf[kt] = *(const bf16x8*)(pf + kt * 32);
      }
      float* sp = &slots[w & 3][0][lane][0];
#pragma unroll
      for (int mi = 0; mi < 8; ++mi)
        *(f32x4*)(sp + mi * 256) = acc[mi];
      asm volatile("s_waitcnt lgkmcnt(0)" ::: "memory");
      if (lane == 0) *fprod = w;
    }
  } else {
    // ---- rec consumer: hid_w = relu(slot[w] + W5 @ prev) ----
    const unsigned short* w5p = Wb + 3 * 65536 + d * 16384;
    bf16x8 A2[8][4];
#pragma unroll
    for (int mi = 0; mi < 8; ++mi) {
      int c = mi * 16 + n;
#pragma unroll
      for (int kt = 0; kt < 4; ++kt)
        A2[mi][kt] = *(const bf16x8*)(w5p + c * 128 + kt * 32 + q * 8);
    }
    const unsigned short* ccol = act + base;
    unsigned short* outrow = act + base;
    bf16x8 Bp[4];
#pragma unroll
    for (int kt = 0; kt < 4; ++kt) {
      bf16x8 v = *(const bf16x8*)(ccol + kt * 32);
#pragma unroll
      for (int j = 0; j < 8; ++j) {
        unsigned short uv = (unsigned short)v[j];
        if (uv & 0x8000u) v[j] = 0;  // bf16 relu
      }
      Bp[kt] = v;
      *(bf16x8*)(outrow + kt * 32) = v;  // hid col0 = relu(hs col0), in place
    }
    outrow += 128;
#pragma unroll 1
    for (int w = 1; w <= 95; ++w) {
      while (*fprod < w) __builtin_amdgcn_s_sleep(1);
      asm volatile("" ::: "memory");
      const float* sp = &slots[w & 3][0][lane][0];
      f32x4 acc[8];
#pragma unroll
      for (int mi = 0; mi < 8; ++mi)
        acc[mi] = *(const f32x4*)(sp + mi * 256);
#pragma unroll
      for (int kt = 0; kt < 4; ++kt)
#pragma unroll
        for (int mi = 0; mi < 8; ++mi)
          acc[mi] = __builtin_amdgcn_mfma_f32_16x16x32_bf16(A2[mi][kt], Bp[kt],
                                                            acc[mi], 0, 0, 0);
#pragma unroll
      for (int kt = 0; kt < 4; ++kt) {
        unsigned int u0, u1, u2, u3;
        float a0 = fmaxf(acc[2 * kt][0], 0.f);
        float a1 = fmaxf(acc[2 * kt][1], 0.f);
        float a2 = fmaxf(acc[2 * kt][2], 0.f);
        float a3 = fmaxf(acc[2 * kt][3], 0.f);
        float c0 = fmaxf(acc[2 * kt + 1][0], 0.f);
        float c1 = fmaxf(acc[2 * kt + 1][1], 0.f);
        float c2 = fmaxf(acc[2 * kt + 1][2], 0.f);
        float c3 = fmaxf(acc[2 * kt + 1][3], 0.f);
        asm("v_cvt_pk_bf16_f32 %0, %1, %2" : "=v"(u0) : "v"(a0), "v"(a1));
        asm("v_cvt_pk_bf16_f32 %0, %1, %2" : "=v"(u1) : "v"(a2), "v"(a3));
        asm("v_cvt_pk_bf16_f32 %0, %1, %2" : "=v"(u2) : "v"(c0), "v"(c1));
        asm("v_cvt_pk_bf16_f32 %0, %1, %2" : "=v"(u3) : "v"(c2), "v"(c3));
        uint4v uu;
        uu[0] = u0; uu[1] = u1; uu[2] = u2; uu[3] = u3;
        Bp[kt] = __builtin_bit_cast(bf16x8, uu);
        *(bf16x8*)(outrow + kt * 32) = Bp[kt];
      }
      outrow += 128;
      asm volatile("" ::: "memory");
      if (lane == 0) *fcons = w;
    }
  }
}

// ---------------- out = x + unpermute(act) ----------------
__global__ __launch_bounds__(256) void out_kernel(
    const float* __restrict__ x, const unsigned short* __restrict__ act,
    float* __restrict__ out) {
  __shared__ unsigned short tile[128 * 208];
  int bid = blockIdx.x;
  int half = bid & 1;
  int rest = bid >> 1;
  int h = rest % 96;
  int b = rest / 96;
  int wd0 = half * 192;
  int tid = threadIdx.x;
#pragma unroll
  for (int it = 0; it < 12; ++it) {
    int gid = it * 256 + tid;
    int wdl = gid >> 4;
    int cc = gid & 15;              // kappa0 = cc*8
    int wdg = wd0 + wdl;
    int d = wdg & 3, w = wdg >> 2;
    bf16x8 v = *(const bf16x8*)(
        act + ((((size_t)(b * 4 + d) * 96 + h) * 96 + w) * 128 + cc * 8));
    int k = wdl >> 3, off = wdl & 7;
    int ktq = cc >> 2, qq = cc & 3;
#pragma unroll
    for (int j = 0; j < 8; ++j) {
      int c = ktq * 32 + ((j >> 2) << 4) + qq * 4 + (j & 3);
      int ks = k ^ ((c >> 3) & 7);
      tile[c * 208 + ks * 8 + off] = (unsigned short)v[j];
    }
  }
  __syncthreads();
#pragma unroll
  for (int it = 0; it < 12; ++it) {
    int sid = it * 256 + tid;
    int c = sid / 24;
    int k = sid % 24;
    int ks = k ^ ((c >> 3) & 7);
    bf16x8 pk = *(const bf16x8*)&tile[c * 208 + ks * 8];
    size_t o = ((size_t)(b * 128 + c) * 96 + h) * 384 + wd0 + k * 8;
    float4 a0 = *(const float4*)(x + o);
    float4 a1 = *(const float4*)(x + o + 4);
    float4 r0, r1;
    r0.x = a0.x + bf2f((unsigned short)pk[0]);
    r0.y = a0.y + bf2f((unsigned short)pk[1]);
    r0.z = a0.z + bf2f((unsigned short)pk[2]);
    r0.w = a0.w + bf2f((unsigned short)pk[3]);
    r1.x = a1.x + bf2f((unsigned short)pk[4]);
    r1.y = a1.y + bf2f((unsigned short)pk[5]);
    r1.z = a1.z + bf2f((unsigned short)pk[6]);
    r1.w = a1.w + bf2f((unsigned short)pk[7]);
    *(float4*)(out + o) = r0;
    *(float4*)(out + o + 4) = r1;
  }
}

extern "C" void kernel_launch(void* const* d_in, const int* in_sizes, int n_in,
                              void* d_out, int out_size, void* d_ws,
                              size_t ws_size, hipStream_t stream) {
  (void)in_sizes; (void)n_in; (void)out_size; (void)ws_size;
  const float* x  = (const float*)d_in[0];
  const float* W1 = (const float*)d_in[1];
  const float* b1 = (const float*)d_in[2];
  const float* W2 = (const float*)d_in[3];
  const float* b2 = (const float*)d_in[4];
  const float* W4 = (const float*)d_in[5];
  const float* b4 = (const float*)d_in[6];
  const float* W5 = (const float*)d_in[7];
  const float* b5 = (const float*)d_in[8];
  float* out = (float*)d_out;

  char* ws = (char*)d_ws;
  unsigned short* Wb  = (unsigned short*)(ws);            // 524288 B
  float* bs12         = (float*)(ws + 524288);            // 2048 B
  float* bs45         = (float*)(ws + 526336);            // 2048 B
  unsigned short* act = (unsigned short*)(ws + 528384);   // 75497472 B

  prep_kernel<<<(4 * 65536 + 1024 + 255) / 256, 256, 0, stream>>>(
      W1, b1, W2, b2, W4, b4, W5, b5, Wb, bs12, bs45);
  transpose_kernel<<<8 * 96 * 2, 256, 0, stream>>>(x, act);
  row_kernel<<<192, 128, 0, stream>>>(act, Wb, bs12);
  col_kernel<<<192, 128, 0, stream>>>(act, Wb, bs45);
  out_kernel<<<8 * 96 * 2, 256, 0, stream>>>(x, act, out);
}